// Round 3
// baseline (1006.680 us; speedup 1.0000x reference)
//
#include <hip/hip_runtime.h>
#include <cstddef>

#define PI2F 6.283185307179586f

// ============================ GEMM (M=16384, N=512, K=512) ============================
template<bool TOUT>
__global__ __launch_bounds__(256)
void gemm_bias_k(const float* __restrict__ X, const float* __restrict__ W,
                 const float* __restrict__ bias, float* __restrict__ out)
{
    __shared__ float As[16][68];
    __shared__ float Bs[16][68];
    __shared__ float Cs[64][68];
    const int tid = threadIdx.x;
    const int i = tid >> 4, j = tid & 15;
    const int m0 = blockIdx.x << 6, n0 = blockIdx.y << 6;
    const int lm = tid >> 2, lkq = tid & 3;
    const int lkk = tid >> 4, lnq = tid & 15;
    const float* Xp = X + (size_t)(m0 + lm) * 512 + lkq * 4;
    const float* Wp = W + (size_t)lkk * 512 + n0 + lnq * 4;
    float c[4][4] = {};
    for (int k0 = 0; k0 < 512; k0 += 16) {
        float4 a4 = *(const float4*)(Xp + k0);
        float4 b4 = *(const float4*)(Wp + (size_t)k0 * 512);
        As[lkq*4+0][lm] = a4.x;
        As[lkq*4+1][lm] = a4.y;
        As[lkq*4+2][lm] = a4.z;
        As[lkq*4+3][lm] = a4.w;
        *(float4*)&Bs[lkk][lnq*4] = b4;
        __syncthreads();
#pragma unroll
        for (int kk = 0; kk < 16; ++kk) {
            float4 av = *(const float4*)&As[kk][i*4];
            float4 bv = *(const float4*)&Bs[kk][j*4];
            float a[4] = {av.x, av.y, av.z, av.w};
            float b[4] = {bv.x, bv.y, bv.z, bv.w};
#pragma unroll
            for (int ii = 0; ii < 4; ++ii)
#pragma unroll
                for (int jj = 0; jj < 4; ++jj)
                    c[ii][jj] = fmaf(a[ii], b[jj], c[ii][jj]);
        }
        __syncthreads();
    }
    if constexpr (TOUT) {
        float bv[4];
#pragma unroll
        for (int r = 0; r < 4; ++r) bv[r] = bias[n0 + j*4 + r];
#pragma unroll
        for (int ii = 0; ii < 4; ++ii)
#pragma unroll
            for (int jj = 0; jj < 4; ++jj)
                Cs[j*4+jj][i*4+ii] = c[ii][jj] + bv[jj];
        __syncthreads();
        const int b_ = m0 >> 10, t0 = m0 & 1023;
        const int col = tid >> 2, seg = tid & 3;
        const int gc = n0 + col;
        const int h = gc & 7, e = gc >> 3;
        float* dst = out + (((size_t)(b_*8 + h) * 64 + e) << 10) + t0;
#pragma unroll
        for (int it = 0; it < 4; ++it) {
            int tl = (it*4 + seg) * 4;
            *(float4*)(dst + tl) = *(float4*)&Cs[col][tl];
        }
    } else {
#pragma unroll
        for (int ii = 0; ii < 4; ++ii) {
            float4 v;
            v.x = c[ii][0] + bias[n0 + j*4 + 0];
            v.y = c[ii][1] + bias[n0 + j*4 + 1];
            v.z = c[ii][2] + bias[n0 + j*4 + 2];
            v.w = c[ii][3] + bias[n0 + j*4 + 3];
            *(float4*)(out + (size_t)(m0 + i*4 + ii) * 512 + n0 + j*4) = v;
        }
    }
}

// ============================ fully-fused wavelet chain + per-level rfft modes ============================
// ONE launch. block = (tensor, b, e); 2048 blocks, 256 threads.
// All 9 levels' d/s chains live in LDS; only QF/KF mode arrays go to global.
// QF/KF packed layout: level l at float2 offset 8192*pre[l], element [row*m_l + j],
// row = (b*8+h)*64+e, pre = {0,16,32,48,64,80,88,92,94}.
__global__ __launch_bounds__(256)
void wavelet_fft_all_k(const float* __restrict__ qin, const float* __restrict__ kin,
                       float2* __restrict__ QFd, float2* __restrict__ KFd,
                       float2* __restrict__ QFs, float2* __restrict__ KFs,
                       const float* __restrict__ ecd, const float* __restrict__ ecs)
{
    __shared__ float bufA[8][1032];   // 1032 % 32 == 8 -> h-offsets hit distinct banks
    __shared__ float bufB[8][520];    // 520 % 32 == 8
    __shared__ float bufD[8][520];
    __shared__ float fd[128], fs[128];
    const int tid = threadIdx.x;
    const int tensor = blockIdx.x >> 10;
    const int b = (blockIdx.x >> 6) & 15;
    const int e = blockIdx.x & 63;
    const float* in = tensor ? kin : qin;
    if (tid < 128) fd[tid] = ecd[tid];
    else fs[tid - 128] = ecs[tid - 128];

    // load the 8 h-rows (1024 floats each) of this (b,e) column
    for (int u = tid; u < 2048; u += 256) {
        int h = u >> 8, q4 = u & 255;
        float4 val = *(const float4*)(in + ((size_t)((b*8 + h) * 64 + e)) * 1024 + q4 * 4);
        *(float4*)&bufA[h][q4 * 4] = val;
    }
    __syncthreads();

    float* cur = &bufA[0][0]; int cs = 1032;
    float* pD = &bufD[0][0];
    const int p  = tid >> 7;
    const int hh = (tid >> 4) & 7;
    const int j  = tid & 15;

    for (int lvl = 0; lvl < 9; ++lvl) {
        const int L = 512 >> lvl;
        const int m = (L / 2 < 16) ? L / 2 : 16;
        float* sOut; int ss;
        if (cur == &bufA[0][0]) { sOut = &bufB[0][0]; ss = 520; }
        else                    { sOut = &bufA[0][0]; ss = 1032; }

        // wavelet: thread = t
        for (int t = tid; t < L; t += 256) {
            float xa[16];
#pragma unroll
            for (int h = 0; h < 8; ++h) {
                xa[h]     = cur[h * cs + 2 * t];
                xa[8 + h] = cur[h * cs + 2 * t + 1];
            }
#pragma unroll
            for (int jj = 0; jj < 8; ++jj) {
                float ad = 0.f, as_ = 0.f;
#pragma unroll
                for (int rr = 0; rr < 16; ++rr) {
                    ad  = fmaf(xa[rr], fd[rr * 8 + jj], ad);
                    as_ = fmaf(xa[rr], fs[rr * 8 + jj], as_);
                }
                pD[jj * 520 + t]  = ad;
                sOut[jj * ss + t] = as_;
            }
        }
        __syncthreads();

        // rfft modes: thread = (path p, row hh, mode j)
        if (j < m) {
            const float* src = p ? (sOut + hh * ss) : (pD + hh * 520);
            const float th = (PI2F / (float)L) * (float)j;
            float re = 0.f, im = 0.f;
            for (int t0 = 0; t0 < L; t0 += 128) {
                float c1, s1_, cj, sj;
                sincosf(th, &s1_, &c1);
                sincosf(th * (float)t0, &sj, &cj);
                int te = (t0 + 128 < L) ? t0 + 128 : L;
                for (int t = t0; t < te; ++t) {
                    float x = src[t];
                    re = fmaf(x, cj, re);
                    im = fmaf(-x, sj, im);
                    float cn = fmaf(cj, c1, -sj * s1_);
                    sj = fmaf(sj, c1, cj * s1_);
                    cj = cn;
                }
            }
            const int pre = lvl <= 5 ? 16 * lvl : (lvl == 6 ? 88 : (lvl == 7 ? 92 : 94));
            float2* dst = tensor ? (p ? KFs : KFd) : (p ? QFs : QFd);
            size_t row = (size_t)(b * 8 + hh) * 64 + e;
            dst[(size_t)8192 * pre + row * (size_t)m + j] = make_float2(re, im);
        }
        __syncthreads();
        cur = sOut; cs = ss;
    }
}

// ============================ fused combine (tanh attention) + dual irfft — ALL levels ============================
// ONE launch: 9 levels x 256 blocks = 2304 blocks. block -> (lvl, bh, half).
__global__ __launch_bounds__(256)
void combine_irfft_all_k(const float2* __restrict__ QFdG, const float2* __restrict__ KFdG,
                         const float2* __restrict__ QFsG, const float2* __restrict__ KFsG,
                         float* __restrict__ USg, float* __restrict__ UDg)
{
    const int lvl   = blockIdx.x >> 8;
    const int inner = blockIdx.x & 255;
    const int half  = inner & 1;
    const int bh    = inner >> 1;
    const int L = 512 >> lvl;
    const int m = (L / 2 < 16) ? L / 2 : 16;
    const int pre = lvl <= 5 ? 16 * lvl : (lvl == 6 ? 88 : (lvl == 7 ? 92 : 94));
    const size_t moff = (size_t)8192 * pre;
    const size_t uoff = (size_t)8192 * (1024 - 2 * L);
    const float scale = 1.f / (4096.f * (float)L);

    __shared__ float2 Qs[2][64 * 16];
    __shared__ float2 Ks[2][64 * 16];
    __shared__ float2 Ss[2][16 * 16];
    __shared__ float2 Us[2][64 * 16];
    const int tid = threadIdx.x;
    const int tot = 64 * m;
    {
        const float4* g0 = (const float4*)(QFdG + moff + (size_t)bh * tot);
        const float4* g1 = (const float4*)(KFdG + moff + (size_t)bh * tot);
        const float4* g2 = (const float4*)(QFsG + moff + (size_t)bh * tot);
        const float4* g3 = (const float4*)(KFsG + moff + (size_t)bh * tot);
        int n4 = tot >> 1;
        for (int u = tid; u < n4; u += 256) {
            ((float4*)Qs[0])[u] = g0[u];
            ((float4*)Ks[0])[u] = g1[u];
            ((float4*)Qs[1])[u] = g2[u];
            ((float4*)Ks[1])[u] = g3[u];
        }
    }
    __syncthreads();
    // S = tanh(QF^T KF) (complex), per path
    const int mm = m * m;
    for (int idx = tid; idx < 2 * mm; idx += 256) {
        int pp = idx / mm;
        int r = idx - pp * mm;
        int x = r / m, y = r - (r / m) * m;
        const float2* Qp = Qs[pp];
        const float2* Kp = Ks[pp];
        float sr = 0.f, si = 0.f;
        for (int ee = 0; ee < 64; ++ee) {
            float2 qq = Qp[ee * m + x], kk = Kp[ee * m + y];
            sr = fmaf(qq.x, kk.x, sr); sr = fmaf(-qq.y, kk.y, sr);
            si = fmaf(qq.x, kk.y, si); si = fmaf(qq.y, kk.x, si);
        }
        float twoa = fminf(fmaxf(2.f * sr, -30.f), 30.f);
        float e2 = expf(twoa);
        float inv = 1.f / e2;
        float s2b, c2b;
        sincosf(2.f * si, &s2b, &c2b);
        float den = 0.5f * (e2 + inv) + c2b;
        Ss[pp][x * 16 + y] = make_float2(0.5f * (e2 - inv) / den, s2b / den);
    }
    __syncthreads();
    // U[p][e][x] = sum_y S[p][x][y] * KF[p][e][y]
    for (int idx = tid; idx < 2 * tot; idx += 256) {
        int pp = idx / tot;
        int r = idx - pp * tot;
        int ee = r / m, x = r - (r / m) * m;
        const float2* Kp = Ks[pp];
        const float2* Sp = Ss[pp];
        float ur = 0.f, ui = 0.f;
        for (int y = 0; y < m; ++y) {
            float2 tt = Sp[x * 16 + y], kk = Kp[ee * m + y];
            ur = fmaf(tt.x, kk.x, ur); ur = fmaf(-tt.y, kk.y, ur);
            ui = fmaf(tt.x, kk.y, ui); ui = fmaf(tt.y, kk.x, ui);
        }
        Us[pp][ee * m + x] = make_float2(ur, ui);
    }
    __syncthreads();
    for (int idx = tid; idx < tot; idx += 256) {
        float2 a = Us[0][idx], bb = Us[1][idx];
        Us[1][idx] = make_float2(a.x + bb.x, a.y + bb.y);
    }
    __syncthreads();
    // dual irfft over this block's 32 e-rows
    const int eBase = half * 32;
    for (int u = tid; u < 32 * L; u += 256) {
        int ee = eBase + u / L;
        int t = u - (u / L) * L;
        const float2* Wd = Us[0] + ee * m;
        const float2* Wv = Us[1] + ee * m;
        float as_ = Wd[0].x;
        float ad_ = Wv[0].x;
        if (m > 1) {
            float s1, c1;
            __sincosf((PI2F / (float)L) * (float)t, &s1, &c1);
            float cj = c1, sj = s1;
            for (int jj = 1; jj < m; ++jj) {
                float2 dm = Wd[jj], vm = Wv[jj];
                as_ += 2.f * (dm.x * cj - dm.y * sj);
                ad_ += 2.f * (vm.x * cj - vm.y * sj);
                float cn = fmaf(cj, c1, -sj * s1);
                sj = fmaf(sj, c1, cj * s1);
                cj = cn;
            }
        }
        size_t row = (size_t)bh * 64 + ee;
        USg[uoff + row * (size_t)L + t] = as_ * scale;
        UDg[uoff + row * (size_t)L + t] = ad_ * scale;
    }
}

// ============================ fully-fused reconstruction chain ============================
// ONE launch. block = (b, e); 1024 blocks, 256 threads. v chain lives in LDS.
// In-place interleave is safe processing chunks in descending t order (writes land at >= 2t).
__global__ __launch_bounds__(256)
void recon_all_k(const float* __restrict__ USg, const float* __restrict__ UDg,
                 const float* __restrict__ rce, const float* __restrict__ rco,
                 float* __restrict__ vT)
{
    __shared__ float v[8][1032];
    __shared__ float se[16][8];
    __shared__ float so[16][8];
    const int tid = threadIdx.x;
    const int b = blockIdx.x >> 6;
    const int e = blockIdx.x & 63;
    if (tid < 128) se[tid >> 3][tid & 7] = rce[tid];
    else { int u = tid - 128; so[u >> 3][u & 7] = rco[u]; }
    if (tid < 16) v[tid >> 1][tid & 1] = 0.f;
    __syncthreads();

    for (int i = 8; i >= 0; --i) {
        const int L = 512 >> i;
        const size_t uoff = (size_t)8192 * (1024 - 2 * L);
        const int nC = (L + 255) >> 8;
        for (int c = nC - 1; c >= 0; --c) {
            const int t = (c << 8) + tid;
            float a[16];
            const bool act = t < L;
            if (act) {
#pragma unroll
                for (int h = 0; h < 8; ++h) {
                    size_t pgl = uoff + ((size_t)((b*8 + h) * 64 + e)) * (size_t)L + t;
                    a[h]     = v[h][t] + USg[pgl];
                    a[8 + h] = UDg[pgl];
                }
            }
            __syncthreads();
            if (act) {
#pragma unroll
                for (int jj = 0; jj < 8; ++jj) {
                    float ev = 0.f, od = 0.f;
#pragma unroll
                    for (int rr = 0; rr < 16; ++rr) {
                        ev = fmaf(a[rr], se[rr][jj], ev);
                        od = fmaf(a[rr], so[rr][jj], od);
                    }
                    v[jj][2 * t]     = ev;
                    v[jj][2 * t + 1] = od;
                }
            }
            __syncthreads();
        }
    }
    // write final v (8 x 1024) to global in T layout
    for (int u = tid; u < 2048; u += 256) {
        int h = u >> 8, q4 = u & 255;
        float4 val = *(float4*)&v[h][q4 * 4];
        *(float4*)(vT + ((size_t)((b*8 + h) * 64 + e)) * 1024 + q4 * 4) = val;
    }
}

// ============================ transpose T[b][h][e][t] -> N[b][t][e*8+h] ============================
__global__ __launch_bounds__(256)
void trans_tn_k(const float* __restrict__ vT, float* __restrict__ vN)
{
    __shared__ float Ls[512][17];
    const int b = blockIdx.x >> 6;
    const int t0 = (blockIdx.x & 63) << 4;
    const int tid = threadIdx.x;
#pragma unroll
    for (int it = 0; it < 8; ++it) {
        int u = it * 256 + tid;
        int row = u >> 2, part = u & 3;
        float4 v = *(const float4*)(vT + ((size_t)b * 512 + row) * 1024 + t0 + part * 4);
        Ls[row][part*4+0] = v.x;
        Ls[row][part*4+1] = v.y;
        Ls[row][part*4+2] = v.z;
        Ls[row][part*4+3] = v.w;
    }
    __syncthreads();
#pragma unroll
    for (int it = 0; it < 8; ++it) {
        int u = it * 256 + tid;
        int cq = u & 127, tt = u >> 7;
        int c = cq * 4;
        float4 v;
        v.x = Ls[(((c+0) & 7) << 6) + ((c+0) >> 3)][tt];
        v.y = Ls[(((c+1) & 7) << 6) + ((c+1) >> 3)][tt];
        v.z = Ls[(((c+2) & 7) << 6) + ((c+2) >> 3)][tt];
        v.w = Ls[(((c+3) & 7) << 6) + ((c+3) >> 3)][tt];
        *(float4*)(vN + ((size_t)b * 1024 + t0 + tt) * 512 + c) = v;
    }
}

// ============================ driver ============================
extern "C" void kernel_launch(void* const* d_in, const int* in_sizes, int n_in,
                              void* d_out, int out_size, void* d_ws, size_t ws_size,
                              hipStream_t stream)
{
    const float* q    = (const float*)d_in[0];
    const float* k    = (const float*)d_in[1];
    const float* Lq_w = (const float*)d_in[3];
    const float* Lq_b = (const float*)d_in[4];
    const float* Lk_w = (const float*)d_in[5];
    const float* Lk_b = (const float*)d_in[6];
    const float* outw = (const float*)d_in[9];
    const float* outb = (const float*)d_in[10];
    const float* ec_s = (const float*)d_in[11];
    const float* ec_d = (const float*)d_in[12];
    const float* rc_e = (const float*)d_in[13];
    const float* rc_o = (const float*)d_in[14];

    float* ws = (float*)d_ws;
    float*  qA   = ws;                       // 8,388,608 floats (proj q, later vT)
    float*  kA   = qA + 8388608;             // 8,388,608 floats (proj k, later vN)
    float*  US   = kA + 8388608;             // 8,380,416 floats
    float*  UD   = US + 8380416;             // 8,380,416 floats
    float2* QFd  = (float2*)(UD + 8380416);  // 778,240 float2 each (8192 rows x 95 modes)
    float2* KFd  = QFd + 778240;
    float2* QFs  = KFd + 778240;
    float2* KFs  = QFs + 778240;

    // ---- input projections (v path is dead code: FCA never reads v) ----
    dim3 gg(256, 8);
    gemm_bias_k<true><<<gg, 256, 0, stream>>>(q, Lq_w, Lq_b, qA);
    gemm_bias_k<true><<<gg, 256, 0, stream>>>(k, Lk_w, Lk_b, kA);

    // ---- all 9 wavelet+fft levels, one launch ----
    wavelet_fft_all_k<<<2048, 256, 0, stream>>>(qA, kA, QFd, KFd, QFs, KFs, ec_d, ec_s);

    // ---- all 9 combine+irfft levels, one launch ----
    combine_irfft_all_k<<<2304, 256, 0, stream>>>(QFd, KFd, QFs, KFs, US, UD);

    // ---- full reconstruction chain, one launch (writes vT into qA) ----
    recon_all_k<<<1024, 256, 0, stream>>>(US, UD, rc_e, rc_o, qA);

    // ---- T -> N, final GEMM ----
    trans_tn_k<<<1024, 256, 0, stream>>>(qA, kA);
    gemm_bias_k<false><<<gg, 256, 0, stream>>>(kA, outw, outb, (float*)d_out);
}

// Round 4
// 990.324 us; speedup vs baseline: 1.0165x; 1.0165x over previous
//
#include <hip/hip_runtime.h>
#include <cstddef>

#define PI2F 6.283185307179586f

// ---- workspace layout (float offsets) ----
#define QA_OFF   0u                      // 8,388,608  proj q (later US)
#define KA_OFF   8388608u                // 8,388,608  proj k (later UD)
#define CH_OFF   16777216u               // 33,488,896 chains (later vT, vN)
#define MF_OFF   (CH_OFF + 33488896u)    // 9,437,184  fwd modes
#define MUS_OFF  (MF_OFF + 9437184u)     // 2,359,296  us modes
#define MUD_OFF  (MUS_OFF + 2359296u)    // 2,359,296  ud modes
#define WF_OFF   (MUD_OFF + 2359296u)    // 32,704     fwd twiddles
#define WI_OFF   (WF_OFF + 32704u)       // 32,704     inv twiddles

// ============================ GEMM (M=16384, N=512, K=512) ============================
template<bool TOUT>
__global__ __launch_bounds__(256)
void gemm_bias_k(const float* __restrict__ X, const float* __restrict__ W,
                 const float* __restrict__ bias, float* __restrict__ out)
{
    __shared__ float As[16][68];
    __shared__ float Bs[16][68];
    __shared__ float Cs[64][68];
    const int tid = threadIdx.x;
    const int i = tid >> 4, j = tid & 15;
    const int m0 = blockIdx.x << 6, n0 = blockIdx.y << 6;
    const int lm = tid >> 2, lkq = tid & 3;
    const int lkk = tid >> 4, lnq = tid & 15;
    const float* Xp = X + (size_t)(m0 + lm) * 512 + lkq * 4;
    const float* Wp = W + (size_t)lkk * 512 + n0 + lnq * 4;
    float c[4][4] = {};
    for (int k0 = 0; k0 < 512; k0 += 16) {
        float4 a4 = *(const float4*)(Xp + k0);
        float4 b4 = *(const float4*)(Wp + (size_t)k0 * 512);
        As[lkq*4+0][lm] = a4.x;
        As[lkq*4+1][lm] = a4.y;
        As[lkq*4+2][lm] = a4.z;
        As[lkq*4+3][lm] = a4.w;
        *(float4*)&Bs[lkk][lnq*4] = b4;
        __syncthreads();
#pragma unroll
        for (int kk = 0; kk < 16; ++kk) {
            float4 av = *(const float4*)&As[kk][i*4];
            float4 bv = *(const float4*)&Bs[kk][j*4];
            float a[4] = {av.x, av.y, av.z, av.w};
            float b[4] = {bv.x, bv.y, bv.z, bv.w};
#pragma unroll
            for (int ii = 0; ii < 4; ++ii)
#pragma unroll
                for (int jj = 0; jj < 4; ++jj)
                    c[ii][jj] = fmaf(a[ii], b[jj], c[ii][jj]);
        }
        __syncthreads();
    }
    if constexpr (TOUT) {
        float bv[4];
#pragma unroll
        for (int r = 0; r < 4; ++r) bv[r] = bias[n0 + j*4 + r];
#pragma unroll
        for (int ii = 0; ii < 4; ++ii)
#pragma unroll
            for (int jj = 0; jj < 4; ++jj)
                Cs[j*4+jj][i*4+ii] = c[ii][jj] + bv[jj];
        __syncthreads();
        const int b_ = m0 >> 10, t0 = m0 & 1023;
        const int col = tid >> 2, seg = tid & 3;
        const int gc = n0 + col;
        const int h = gc & 7, e = gc >> 3;
        float* dst = out + (((size_t)(b_*8 + h) * 64 + e) << 10) + t0;
#pragma unroll
        for (int it = 0; it < 4; ++it) {
            int tl = (it*4 + seg) * 4;
            *(float4*)(dst + tl) = *(float4*)&Cs[col][tl];
        }
    } else {
#pragma unroll
        for (int ii = 0; ii < 4; ++ii) {
            float4 v;
            v.x = c[ii][0] + bias[n0 + j*4 + 0];
            v.y = c[ii][1] + bias[n0 + j*4 + 1];
            v.z = c[ii][2] + bias[n0 + j*4 + 2];
            v.w = c[ii][3] + bias[n0 + j*4 + 3];
            *(float4*)(out + (size_t)(m0 + i*4 + ii) * 512 + n0 + j*4) = v;
        }
    }
}

// ============================ twiddle precompute ============================
// Wf (per level, [L x 32]): col j<16: cos(2pi j t/L); col 16+j: -sin(2pi j t/L)
// Wi (per level, [32 x L]): row 0: 1; row j (1..15): 2cos; row 16: 0; row 16+j: -2sin.
// All Wi scaled by 1/(4096 L). Exact (j*t) mod L integer reduction.
__global__ __launch_bounds__(256)
void twiddle_k(float* __restrict__ Wf, float* __restrict__ Wi)
{
    int idx = blockIdx.x * 256 + threadIdx.x;
    int table = idx / 32704;
    if (table >= 2) return;
    int r = idx - table * 32704;
    int lvl = 0, base = 0;
    for (int l = 0; l < 9; ++l) {
        int Ll = 512 >> l;
        int sz = 32 * Ll;
        if (r < base + sz) { lvl = l; break; }
        base += sz;
    }
    int L = 512 >> lvl;
    int rr = r - base;
    if (table == 0) {
        int t = rr >> 5, c = rr & 31;
        int j = c & 15, isIm = c >> 4;
        int mv = (j * t) & (L - 1);
        float ang = (PI2F / (float)L) * (float)mv;
        float s, cc; sincosf(ang, &s, &cc);
        Wf[r] = isIm ? -s : cc;
    } else {
        int k = rr / L, t = rr - (rr / L) * L;
        int j = k & 15, isIm = k >> 4;
        int mv = (j * t) & (L - 1);
        float ang = (PI2F / (float)L) * (float)mv;
        float s, cc; sincosf(ang, &s, &cc);
        float scale = 1.f / (4096.f * (float)L);
        float v;
        if (!isIm) v = (j == 0) ? 1.f : 2.f * cc;
        else       v = (j == 0) ? 0.f : -2.f * s;
        Wi[r] = v * scale;
    }
}

// ============================ fused wavelet chain -> global chains ============================
// block = (tensor, b, e); 2048 blocks. All 9 levels in LDS; d/s chains written to CH.
// CH element (lvl, a, row, t): base 32768*(1024-2L) + (a*8192 + row)*L + t,
// a = tensor*2 + path(0=d,1=s), row = (b*8+h)*64+e.
__global__ __launch_bounds__(256)
void wavelet_chain_k(const float* __restrict__ qin, const float* __restrict__ kin,
                     float* __restrict__ CH,
                     const float* __restrict__ ecd, const float* __restrict__ ecs)
{
    __shared__ float bufA[8][1032];
    __shared__ float bufB[8][520];
    __shared__ float bufD[8][520];
    __shared__ float fd[128], fs[128];
    const int tid = threadIdx.x;
    const int tensor = blockIdx.x >> 10;
    const int b = (blockIdx.x >> 6) & 15;
    const int e = blockIdx.x & 63;
    const float* in = tensor ? kin : qin;
    if (tid < 128) fd[tid] = ecd[tid];
    else fs[tid - 128] = ecs[tid - 128];

    for (int u = tid; u < 2048; u += 256) {
        int h = u >> 8, q4 = u & 255;
        *(float4*)&bufA[h][q4 * 4] =
            *(const float4*)(in + ((size_t)((b*8 + h) * 64 + e)) * 1024 + q4 * 4);
    }
    __syncthreads();

    float* cur = &bufA[0][0]; int cs = 1032;
    float* pD = &bufD[0][0];
    for (int lvl = 0; lvl < 9; ++lvl) {
        const int L = 512 >> lvl;
        float* sOut; int ss;
        if (cur == &bufA[0][0]) { sOut = &bufB[0][0]; ss = 520; }
        else                    { sOut = &bufA[0][0]; ss = 1032; }

        for (int t = tid; t < L; t += 256) {
            float xa[16];
#pragma unroll
            for (int h = 0; h < 8; ++h) {
                xa[h]     = cur[h * cs + 2 * t];
                xa[8 + h] = cur[h * cs + 2 * t + 1];
            }
#pragma unroll
            for (int jj = 0; jj < 8; ++jj) {
                float ad = 0.f, as_ = 0.f;
#pragma unroll
                for (int rr = 0; rr < 16; ++rr) {
                    ad  = fmaf(xa[rr], fd[rr * 8 + jj], ad);
                    as_ = fmaf(xa[rr], fs[rr * 8 + jj], as_);
                }
                pD[jj * 520 + t]  = ad;
                sOut[jj * ss + t] = as_;
            }
        }
        __syncthreads();

        // write both chains to global
        const size_t chb = (size_t)32768 * (size_t)(1024 - 2 * L);
        if (L >= 4) {
            const int nv = 4 * L;   // float4 count over 2 paths x 8 h x L
            for (int u = tid; u < nv; u += 256) {
                int u4 = u * 4;
                int p = u4 / (8 * L);
                int rem = u4 - p * 8 * L;
                int h = rem / L;
                int t4 = rem - h * L;
                float4 v = p ? *(float4*)(sOut + h * ss + t4)
                             : *(float4*)(pD + h * 520 + t4);
                size_t row = (size_t)((tensor * 2 + p) * 8192) + (size_t)(b*8 + h) * 64 + e;
                *(float4*)(CH + chb + row * (size_t)L + t4) = v;
            }
        } else {  // L == 2
            for (int u = tid; u < 16 * L; u += 256) {
                int p = u / (8 * L);
                int rem = u - p * 8 * L;
                int h = rem / L;
                int t = rem - h * L;
                float v = p ? sOut[h * ss + t] : pD[h * 520 + t];
                size_t row = (size_t)((tensor * 2 + p) * 8192) + (size_t)(b*8 + h) * 64 + e;
                CH[chb + row * (size_t)L + t] = v;
            }
        }
        __syncthreads();
        cur = sOut; cs = ss;
    }
}

// ============================ forward DFT as GEMM ============================
// MF[lvl][row x 32] = CH[lvl][row x L] . Wf[lvl][L x 32], rows = 32768.
// grid = 9 levels x 128 blocks; each block: 4 row-tiles of 64.
__global__ __launch_bounds__(256)
void fwd_dft_k(const float* __restrict__ CH, const float* __restrict__ Wf,
               float* __restrict__ MF)
{
    __shared__ float Bs[16384];
    __shared__ float As[64][33];
    const int tid = threadIdx.x;
    const int lvl = blockIdx.x >> 7;
    const int blk = blockIdx.x & 127;
    const int L = 512 >> lvl;
    const size_t chb = (size_t)32768 * (size_t)(1024 - 2 * L);
    const int wb = 32 * (1024 - 2 * L);
    const size_t mfb = (size_t)lvl * 1048576;
    const int n = 32 * L;
    for (int u = tid * 4; u < n; u += 1024)
        *(float4*)&Bs[u] = *(const float4*)&Wf[wb + u];
    __syncthreads();
    const int r = tid & 63, g = tid >> 6;
    for (int tile = blk; tile < 512; tile += 128) {
        const size_t rowb = (size_t)tile * 64;
        float acc[8] = {0,0,0,0,0,0,0,0};
        for (int k0 = 0; k0 < L; k0 += 32) {
            const int kw = (L - k0 < 32) ? (L - k0) : 32;
            __syncthreads();
            if (kw >= 4) {
                const int kq = kw >> 2;
                const int nv = 64 * kq;
                for (int u = tid; u < nv; u += 256) {
                    int r2 = u / kq, q = u - (u / kq) * kq;
                    float4 v = *(const float4*)(CH + chb + (rowb + r2) * (size_t)L + k0 + q * 4);
                    As[r2][q*4+0] = v.x; As[r2][q*4+1] = v.y;
                    As[r2][q*4+2] = v.z; As[r2][q*4+3] = v.w;
                }
            } else {  // kw == 2 (L == 2)
                for (int u = tid; u < 128; u += 256) {
                    int r2 = u >> 1, t = u & 1;
                    As[r2][t] = CH[chb + (rowb + r2) * (size_t)L + t];
                }
            }
            __syncthreads();
            for (int kk = 0; kk < kw; ++kk) {
                float a = As[r][kk];
                float4 b0 = *(const float4*)&Bs[(k0 + kk) * 32 + g * 8];
                float4 b1 = *(const float4*)&Bs[(k0 + kk) * 32 + g * 8 + 4];
                acc[0] = fmaf(a, b0.x, acc[0]);
                acc[1] = fmaf(a, b0.y, acc[1]);
                acc[2] = fmaf(a, b0.z, acc[2]);
                acc[3] = fmaf(a, b0.w, acc[3]);
                acc[4] = fmaf(a, b1.x, acc[4]);
                acc[5] = fmaf(a, b1.y, acc[5]);
                acc[6] = fmaf(a, b1.z, acc[6]);
                acc[7] = fmaf(a, b1.w, acc[7]);
            }
        }
        float4 s0 = {acc[0], acc[1], acc[2], acc[3]};
        float4 s1 = {acc[4], acc[5], acc[6], acc[7]};
        *(float4*)(MF + mfb + (rowb + r) * 32 + g * 8)     = s0;
        *(float4*)(MF + mfb + (rowb + r) * 32 + g * 8 + 4) = s1;
    }
}

// ============================ combine: S = tanh(QF^T KF), U = S.KF ============================
// grid = 9 levels x 128 bh. Outputs us-modes (d path) and ud-modes (d+s), zero-padded to 16.
__global__ __launch_bounds__(256)
void combine2_k(const float* __restrict__ MF, float* __restrict__ MUS, float* __restrict__ MUD)
{
    __shared__ float F[4][64][33];
    __shared__ float Sre[2][16][17], Sim[2][16][17];
    const int tid = threadIdx.x;
    const int lvl = blockIdx.x >> 7;
    const int bh = blockIdx.x & 127;
    const int L = 512 >> lvl;
    const int m = (L / 2 < 16) ? L / 2 : 16;
    const size_t mfb = (size_t)lvl * 1048576;
    // arrays: 0=q-d, 1=q-s, 2=k-d, 3=k-s
    for (int a = 0; a < 4; ++a) {
        const float* src = MF + mfb + ((size_t)a * 8192 + (size_t)bh * 64) * 32;
        for (int u = tid; u < 512; u += 256) {
            float4 v = *(const float4*)(src + u * 4);
            int ee = (u * 4) >> 5, c = (u * 4) & 31;
            F[a][ee][c] = v.x; F[a][ee][c+1] = v.y; F[a][ee][c+2] = v.z; F[a][ee][c+3] = v.w;
        }
    }
    __syncthreads();
    const int mm = m * m;
    for (int idx = tid; idx < 2 * mm; idx += 256) {
        int p = idx / mm, rr = idx - p * mm;
        int x = rr / m, y = rr - (rr / m) * m;
        float sr = 0.f, si = 0.f;
        for (int ee = 0; ee < 64; ++ee) {
            float qre = F[p][ee][x],     qim = F[p][ee][16 + x];
            float kre = F[2 + p][ee][y], kim = F[2 + p][ee][16 + y];
            sr = fmaf(qre, kre, sr); sr = fmaf(-qim, kim, sr);
            si = fmaf(qre, kim, si); si = fmaf(qim, kre, si);
        }
        float twoa = fminf(fmaxf(2.f * sr, -30.f), 30.f);
        float e2 = expf(twoa), inv = 1.f / e2;
        float s2b, c2b; sincosf(2.f * si, &s2b, &c2b);
        float den = 0.5f * (e2 + inv) + c2b;
        Sre[p][x][y] = 0.5f * (e2 - inv) / den;
        Sim[p][x][y] = s2b / den;
    }
    __syncthreads();
    for (int idx = tid; idx < 1024; idx += 256) {
        int ee = idx >> 4, x = idx & 15;
        float urd = 0.f, uid = 0.f, urs = 0.f, uis = 0.f;
        if (x < m) {
            for (int y = 0; y < m; ++y) {
                float k0re = F[2][ee][y], k0im = F[2][ee][16 + y];
                float k1re = F[3][ee][y], k1im = F[3][ee][16 + y];
                float s0r = Sre[0][x][y], s0i = Sim[0][x][y];
                float s1r = Sre[1][x][y], s1i = Sim[1][x][y];
                urd = fmaf(s0r, k0re, urd); urd = fmaf(-s0i, k0im, urd);
                uid = fmaf(s0r, k0im, uid); uid = fmaf(s0i, k0re, uid);
                urs = fmaf(s1r, k1re, urs); urs = fmaf(-s1i, k1im, urs);
                uis = fmaf(s1r, k1im, uis); uis = fmaf(s1i, k1re, uis);
            }
        }
        size_t mb = (size_t)lvl * 262144 + ((size_t)bh * 64 + ee) * 32;
        MUS[mb + x]      = urd;
        MUS[mb + 16 + x] = uid;
        MUD[mb + x]      = urd + urs;
        MUD[mb + 16 + x] = uid + uis;
    }
}

// ============================ inverse DFT as GEMM ============================
// US/UD[lvl][row x L] = MU[lvl][row x 32] . Wi[lvl][32 x L], rows = 8192 each.
// grid = 9 levels x 128 blocks; block does 2 tiles (one us, one ud).
__global__ __launch_bounds__(256)
void inv_dft_k(const float* __restrict__ MUS, const float* __restrict__ MUD,
               const float* __restrict__ Wi,
               float* __restrict__ US, float* __restrict__ UD)
{
    __shared__ float Bs[16384];
    __shared__ float As[64][33];
    const int tid = threadIdx.x;
    const int lvl = blockIdx.x >> 7;
    const int blk = blockIdx.x & 127;
    const int L = 512 >> lvl;
    const int wb = 32 * (1024 - 2 * L);
    const size_t uoff = (size_t)8192 * (size_t)(1024 - 2 * L);
    const int n = 32 * L;
    for (int u = tid * 4; u < n; u += 1024)
        *(float4*)&Bs[u] = *(const float4*)&Wi[wb + u];
    __syncthreads();
    const int r = tid & 63, g = tid >> 6;
    for (int tile = blk; tile < 256; tile += 128) {
        const int half = tile >> 7;
        const int rowb = (tile & 127) * 64;
        const float* MU = half ? MUD : MUS;
        float* OUT = half ? UD : US;
        __syncthreads();
        {
            const float* src = MU + (size_t)lvl * 262144 + (size_t)rowb * 32;
            for (int u = tid; u < 512; u += 256) {
                float4 v = *(const float4*)(src + u * 4);
                int r2 = (u * 4) >> 5, c = (u * 4) & 31;
                As[r2][c] = v.x; As[r2][c+1] = v.y; As[r2][c+2] = v.z; As[r2][c+3] = v.w;
            }
        }
        __syncthreads();
        float a_reg[32];
#pragma unroll
        for (int kk = 0; kk < 32; ++kk) a_reg[kk] = As[r][kk];
        float* dst = OUT + uoff + (size_t)(rowb + r) * (size_t)L;
        if (L >= 4) {
            const int G = L >> 2;
            for (int i = g; i < G; i += 4) {
                int c0 = i * 4;
                float4 o = {0.f, 0.f, 0.f, 0.f};
#pragma unroll
                for (int kk = 0; kk < 32; ++kk) {
                    float4 bv = *(const float4*)&Bs[kk * L + c0];
                    o.x = fmaf(a_reg[kk], bv.x, o.x);
                    o.y = fmaf(a_reg[kk], bv.y, o.y);
                    o.z = fmaf(a_reg[kk], bv.z, o.z);
                    o.w = fmaf(a_reg[kk], bv.w, o.w);
                }
                *(float4*)(dst + c0) = o;
            }
        } else {  // L == 2
            if (g == 0) {
                for (int c = 0; c < 2; ++c) {
                    float o = 0.f;
#pragma unroll
                    for (int kk = 0; kk < 32; ++kk)
                        o = fmaf(a_reg[kk], Bs[kk * 2 + c], o);
                    dst[c] = o;
                }
            }
        }
    }
}

// ============================ fully-fused reconstruction chain ============================
__global__ __launch_bounds__(256)
void recon_all_k(const float* __restrict__ USg, const float* __restrict__ UDg,
                 const float* __restrict__ rce, const float* __restrict__ rco,
                 float* __restrict__ vT)
{
    __shared__ float v[8][1032];
    __shared__ float se[16][8];
    __shared__ float so[16][8];
    const int tid = threadIdx.x;
    const int b = blockIdx.x >> 6;
    const int e = blockIdx.x & 63;
    if (tid < 128) se[tid >> 3][tid & 7] = rce[tid];
    else { int u = tid - 128; so[u >> 3][u & 7] = rco[u]; }
    if (tid < 16) v[tid >> 1][tid & 1] = 0.f;
    __syncthreads();

    for (int i = 8; i >= 0; --i) {
        const int L = 512 >> i;
        const size_t uoff = (size_t)8192 * (1024 - 2 * L);
        const int nC = (L + 255) >> 8;
        for (int c = nC - 1; c >= 0; --c) {
            const int t = (c << 8) + tid;
            float a[16];
            const bool act = t < L;
            if (act) {
#pragma unroll
                for (int h = 0; h < 8; ++h) {
                    size_t pgl = uoff + ((size_t)((b*8 + h) * 64 + e)) * (size_t)L + t;
                    a[h]     = v[h][t] + USg[pgl];
                    a[8 + h] = UDg[pgl];
                }
            }
            __syncthreads();
            if (act) {
#pragma unroll
                for (int jj = 0; jj < 8; ++jj) {
                    float ev = 0.f, od = 0.f;
#pragma unroll
                    for (int rr = 0; rr < 16; ++rr) {
                        ev = fmaf(a[rr], se[rr][jj], ev);
                        od = fmaf(a[rr], so[rr][jj], od);
                    }
                    v[jj][2 * t]     = ev;
                    v[jj][2 * t + 1] = od;
                }
            }
            __syncthreads();
        }
    }
    for (int u = tid; u < 2048; u += 256) {
        int h = u >> 8, q4 = u & 255;
        float4 val = *(float4*)&v[h][q4 * 4];
        *(float4*)(vT + ((size_t)((b*8 + h) * 64 + e)) * 1024 + q4 * 4) = val;
    }
}

// ============================ transpose T[b][h][e][t] -> N[b][t][e*8+h] ============================
__global__ __launch_bounds__(256)
void trans_tn_k(const float* __restrict__ vT, float* __restrict__ vN)
{
    __shared__ float Ls[512][17];
    const int b = blockIdx.x >> 6;
    const int t0 = (blockIdx.x & 63) << 4;
    const int tid = threadIdx.x;
#pragma unroll
    for (int it = 0; it < 8; ++it) {
        int u = it * 256 + tid;
        int row = u >> 2, part = u & 3;
        float4 v = *(const float4*)(vT + ((size_t)b * 512 + row) * 1024 + t0 + part * 4);
        Ls[row][part*4+0] = v.x;
        Ls[row][part*4+1] = v.y;
        Ls[row][part*4+2] = v.z;
        Ls[row][part*4+3] = v.w;
    }
    __syncthreads();
#pragma unroll
    for (int it = 0; it < 8; ++it) {
        int u = it * 256 + tid;
        int cq = u & 127, tt = u >> 7;
        int c = cq * 4;
        float4 v;
        v.x = Ls[(((c+0) & 7) << 6) + ((c+0) >> 3)][tt];
        v.y = Ls[(((c+1) & 7) << 6) + ((c+1) >> 3)][tt];
        v.z = Ls[(((c+2) & 7) << 6) + ((c+2) >> 3)][tt];
        v.w = Ls[(((c+3) & 7) << 6) + ((c+3) >> 3)][tt];
        *(float4*)(vN + ((size_t)b * 1024 + t0 + tt) * 512 + c) = v;
    }
}

// ============================ driver ============================
extern "C" void kernel_launch(void* const* d_in, const int* in_sizes, int n_in,
                              void* d_out, int out_size, void* d_ws, size_t ws_size,
                              hipStream_t stream)
{
    const float* q    = (const float*)d_in[0];
    const float* k    = (const float*)d_in[1];
    const float* Lq_w = (const float*)d_in[3];
    const float* Lq_b = (const float*)d_in[4];
    const float* Lk_w = (const float*)d_in[5];
    const float* Lk_b = (const float*)d_in[6];
    const float* outw = (const float*)d_in[9];
    const float* outb = (const float*)d_in[10];
    const float* ec_s = (const float*)d_in[11];
    const float* ec_d = (const float*)d_in[12];
    const float* rc_e = (const float*)d_in[13];
    const float* rc_o = (const float*)d_in[14];

    float* ws = (float*)d_ws;
    float* qA  = ws + QA_OFF;     // proj q; later US
    float* kA  = ws + KA_OFF;     // proj k; later UD
    float* CH  = ws + CH_OFF;     // chains; later vT (first 8.39M) and vN (next 8.39M)
    float* MF  = ws + MF_OFF;
    float* MUS = ws + MUS_OFF;
    float* MUD = ws + MUD_OFF;
    float* Wf  = ws + WF_OFF;
    float* Wi  = ws + WI_OFF;
    float* vT  = CH;
    float* vN  = CH + 8388608;

    twiddle_k<<<256, 256, 0, stream>>>(Wf, Wi);

    dim3 gg(256, 8);
    gemm_bias_k<true><<<gg, 256, 0, stream>>>(q, Lq_w, Lq_b, qA);
    gemm_bias_k<true><<<gg, 256, 0, stream>>>(k, Lk_w, Lk_b, kA);

    wavelet_chain_k<<<2048, 256, 0, stream>>>(qA, kA, CH, ec_d, ec_s);
    fwd_dft_k<<<1152, 256, 0, stream>>>(CH, Wf, MF);
    combine2_k<<<1152, 256, 0, stream>>>(MF, MUS, MUD);
    inv_dft_k<<<1152, 256, 0, stream>>>(MUS, MUD, Wi, qA, kA);   // US := qA, UD := kA
    recon_all_k<<<1024, 256, 0, stream>>>(qA, kA, rc_e, rc_o, vT);
    trans_tn_k<<<1024, 256, 0, stream>>>(vT, vN);
    gemm_bias_k<false><<<gg, 256, 0, stream>>>(vN, outw, outb, (float*)d_out);
}

// Round 5
// 565.337 us; speedup vs baseline: 1.7807x; 1.7517x over previous
//
#include <hip/hip_runtime.h>
#include <cstddef>

#define PI2F 6.283185307179586f

typedef __bf16 bf16_t;
typedef __bf16 bf16x8 __attribute__((ext_vector_type(8)));
typedef float f32x4 __attribute__((ext_vector_type(4)));

// ---- workspace layout (float offsets) ----
#define QA_OFF   0u                      // 8,388,608  proj q (later US)
#define KA_OFF   8388608u                // 8,388,608  proj k (later UD)
#define CH_OFF   16777216u               // 33,488,896 chains (later vT, vN)
#define MF_OFF   (CH_OFF + 33488896u)    // 9,437,184  fwd modes (also hosts WT bf16 tables)
#define MUS_OFF  (MF_OFF + 9437184u)     // 2,359,296  us modes
#define MUD_OFF  (MUS_OFF + 2359296u)    // 2,359,296  ud modes
#define WF_OFF   (MUD_OFF + 2359296u)    // 32,704     fwd twiddles
#define WI_OFF   (WF_OFF + 32704u)       // 32,704     inv twiddles

// ============================ weight prep: transpose + bf16 split ============================
// W[512 k][512 n] fp32 -> WT pair i: hi [n][k] bf16, lo [n][k] bf16
__global__ __launch_bounds__(256)
void wprep_k(const float* __restrict__ Wq, const float* __restrict__ Wk,
             const float* __restrict__ Wo, bf16_t* __restrict__ WT)
{
    __shared__ float T[32][33];
    const int w = blockIdx.x >> 8;
    const int tile = blockIdx.x & 255;
    const int k0 = (tile & 15) * 32, n0 = (tile >> 4) * 32;
    const float* W = (w == 0) ? Wq : (w == 1) ? Wk : Wo;
    bf16_t* oh = WT + (size_t)w * 524288;
    bf16_t* ol = oh + 262144;
    const int tid = threadIdx.x;
    {
        int row = tid >> 3, q = tid & 7;
        float4 v = *(const float4*)(W + (size_t)(k0 + row) * 512 + n0 + q * 4);
        T[row][q*4+0] = v.x; T[row][q*4+1] = v.y; T[row][q*4+2] = v.z; T[row][q*4+3] = v.w;
    }
    __syncthreads();
    {
        int nr = tid >> 3, q = tid & 7;
        union { bf16_t b[4]; uint2 u; } ph, pl;
#pragma unroll
        for (int j = 0; j < 4; ++j) {
            float x = T[q*4+j][nr];
            bf16_t h = (bf16_t)x;
            ph.b[j] = h;
            pl.b[j] = (bf16_t)(x - (float)h);
        }
        size_t dst = (size_t)(n0 + nr) * 512 + k0 + q * 4;
        *(uint2*)&oh[dst] = ph.u;
        *(uint2*)&ol[dst] = pl.u;
    }
}

// ============================ MFMA split-bf16 GEMM (M=16384, N=512, K=512) ============================
// C = X @ W + bias via Xh*Wh + Xh*Wl + Xl*Wh, fp32 accum. 128x128 tile, 4 waves.
template<bool TOUT>
__global__ __launch_bounds__(256)
void mfma_gemm_k(const float* __restrict__ X, const bf16_t* __restrict__ WTh,
                 const bf16_t* __restrict__ WTl, const float* __restrict__ bias,
                 float* __restrict__ out)
{
    __shared__ __align__(16) char smem[40960];
    bf16_t* Ah = (bf16_t*)smem;          // [128][40]
    bf16_t* Al = Ah + 128 * 40;
    bf16_t* Bh = Al + 128 * 40;
    bf16_t* Bl = Bh + 128 * 40;
    float* Cs = (float*)smem;            // [64][132] epilogue overlay
    const int tid = threadIdx.x;
    const int lane = tid & 63;
    const int wv = tid >> 6;
    const int wm = wv & 1, wn = wv >> 1;
    const int m0 = blockIdx.x << 7, n0 = blockIdx.y << 7;
    const int l15 = lane & 15, quad = lane >> 4;

    f32x4 acc[4][4];
    f32x4 zz = {0.f, 0.f, 0.f, 0.f};
#pragma unroll
    for (int i = 0; i < 4; ++i)
#pragma unroll
        for (int j = 0; j < 4; ++j) acc[i][j] = zz;

    for (int kc = 0; kc < 16; ++kc) {
        // stage A (fp32 -> hi/lo bf16)
#pragma unroll
        for (int i = 0; i < 4; ++i) {
            int u = tid + i * 256;
            int row = u >> 3, seg = u & 7;
            float4 v = *(const float4*)(X + (size_t)(m0 + row) * 512 + kc * 32 + seg * 4);
            union { bf16_t b[4]; uint2 u2; } ph, pl;
            float xs[4] = {v.x, v.y, v.z, v.w};
#pragma unroll
            for (int j = 0; j < 4; ++j) {
                bf16_t h = (bf16_t)xs[j];
                ph.b[j] = h;
                pl.b[j] = (bf16_t)(xs[j] - (float)h);
            }
            *(uint2*)&Ah[row * 40 + seg * 4] = ph.u2;
            *(uint2*)&Al[row * 40 + seg * 4] = pl.u2;
        }
        // stage B (pre-split bf16, [n][k] rows)
#pragma unroll
        for (int i = 0; i < 4; ++i) {
            int u = tid + i * 256;
            int variant = u >> 9;
            int rs = u & 511;
            int row = rs >> 2, seg = rs & 3;
            const bf16_t* src = (variant ? WTl : WTh) + (size_t)(n0 + row) * 512 + kc * 32 + seg * 8;
            bf16_t* dst = (variant ? Bl : Bh) + row * 40 + seg * 8;
            *(float4*)dst = *(const float4*)src;
        }
        __syncthreads();
        bf16x8 ah[4], al[4];
#pragma unroll
        for (int mi = 0; mi < 4; ++mi) {
            int row = wm * 64 + mi * 16 + l15;
            ah[mi] = *(bf16x8*)&Ah[row * 40 + quad * 8];
            al[mi] = *(bf16x8*)&Al[row * 40 + quad * 8];
        }
#pragma unroll
        for (int ni = 0; ni < 4; ++ni) {
            int nr = wn * 64 + ni * 16 + l15;
            bf16x8 bh = *(bf16x8*)&Bh[nr * 40 + quad * 8];
            bf16x8 bl = *(bf16x8*)&Bl[nr * 40 + quad * 8];
#pragma unroll
            for (int mi = 0; mi < 4; ++mi) {
                acc[mi][ni] = __builtin_amdgcn_mfma_f32_16x16x32_bf16(ah[mi], bh, acc[mi][ni], 0, 0, 0);
                acc[mi][ni] = __builtin_amdgcn_mfma_f32_16x16x32_bf16(ah[mi], bl, acc[mi][ni], 0, 0, 0);
                acc[mi][ni] = __builtin_amdgcn_mfma_f32_16x16x32_bf16(al[mi], bh, acc[mi][ni], 0, 0, 0);
            }
        }
        __syncthreads();
    }

    if constexpr (TOUT) {
        const int b8 = (m0 >> 10) * 8, tb = m0 & 1023;
        for (int p = 0; p < 2; ++p) {
            if (wn == p) {
#pragma unroll
                for (int ni = 0; ni < 4; ++ni)
#pragma unroll
                    for (int mi = 0; mi < 4; ++mi)
#pragma unroll
                        for (int r = 0; r < 4; ++r) {
                            int nl = ni * 16 + l15;
                            int m = wm * 64 + mi * 16 + quad * 4 + r;
                            Cs[nl * 132 + m] = acc[mi][ni][r];
                        }
            }
            __syncthreads();
#pragma unroll
            for (int i = 0; i < 8; ++i) {
                int u = tid + i * 256;
                int col = u >> 5, seg = u & 31;
                int gc = n0 + p * 64 + col;
                float bz = bias[gc];
                float4 v = *(float4*)&Cs[col * 132 + seg * 4];
                v.x += bz; v.y += bz; v.z += bz; v.w += bz;
                int h = gc & 7, e = gc >> 3;
                *(float4*)(out + (((size_t)(b8 + h)) * 64 + e) * 1024 + tb + seg * 4) = v;
            }
            __syncthreads();
        }
    } else {
#pragma unroll
        for (int ni = 0; ni < 4; ++ni) {
            int n = n0 + wn * 64 + ni * 16 + l15;
            float bz = bias[n];
#pragma unroll
            for (int mi = 0; mi < 4; ++mi)
#pragma unroll
                for (int r = 0; r < 4; ++r) {
                    int m = m0 + wm * 64 + mi * 16 + quad * 4 + r;
                    out[(size_t)m * 512 + n] = acc[mi][ni][r] + bz;
                }
        }
    }
}

// ============================ twiddle precompute ============================
__global__ __launch_bounds__(256)
void twiddle_k(float* __restrict__ Wf, float* __restrict__ Wi)
{
    int idx = blockIdx.x * 256 + threadIdx.x;
    int table = idx / 32704;
    if (table >= 2) return;
    int r = idx - table * 32704;
    int lvl = 0, base = 0;
    for (int l = 0; l < 9; ++l) {
        int Ll = 512 >> l;
        int sz = 32 * Ll;
        if (r < base + sz) { lvl = l; break; }
        base += sz;
    }
    int L = 512 >> lvl;
    int rr = r - base;
    if (table == 0) {
        int t = rr >> 5, c = rr & 31;
        int j = c & 15, isIm = c >> 4;
        int mv = (j * t) & (L - 1);
        float ang = (PI2F / (float)L) * (float)mv;
        float s, cc; sincosf(ang, &s, &cc);
        Wf[r] = isIm ? -s : cc;
    } else {
        int k = rr / L, t = rr - (rr / L) * L;
        int j = k & 15, isIm = k >> 4;
        int mv = (j * t) & (L - 1);
        float ang = (PI2F / (float)L) * (float)mv;
        float s, cc; sincosf(ang, &s, &cc);
        float scale = 1.f / (4096.f * (float)L);
        float v;
        if (!isIm) v = (j == 0) ? 1.f : 2.f * cc;
        else       v = (j == 0) ? 0.f : -2.f * s;
        Wi[r] = v * scale;
    }
}

// ============================ fused wavelet chain -> global chains ============================
__global__ __launch_bounds__(256)
void wavelet_chain_k(const float* __restrict__ qin, const float* __restrict__ kin,
                     float* __restrict__ CH,
                     const float* __restrict__ ecd, const float* __restrict__ ecs)
{
    __shared__ float bufA[8][1032];
    __shared__ float bufB[8][520];
    __shared__ float bufD[8][520];
    __shared__ float fd[128], fs[128];
    const int tid = threadIdx.x;
    const int tensor = blockIdx.x >> 10;
    const int b = (blockIdx.x >> 6) & 15;
    const int e = blockIdx.x & 63;
    const float* in = tensor ? kin : qin;
    if (tid < 128) fd[tid] = ecd[tid];
    else fs[tid - 128] = ecs[tid - 128];

    for (int u = tid; u < 2048; u += 256) {
        int h = u >> 8, q4 = u & 255;
        *(float4*)&bufA[h][q4 * 4] =
            *(const float4*)(in + ((size_t)((b*8 + h) * 64 + e)) * 1024 + q4 * 4);
    }
    __syncthreads();

    float* cur = &bufA[0][0]; int cs = 1032;
    float* pD = &bufD[0][0];
    for (int lvl = 0; lvl < 9; ++lvl) {
        const int L = 512 >> lvl;
        float* sOut; int ss;
        if (cur == &bufA[0][0]) { sOut = &bufB[0][0]; ss = 520; }
        else                    { sOut = &bufA[0][0]; ss = 1032; }

        for (int t = tid; t < L; t += 256) {
            float xa[16];
#pragma unroll
            for (int h = 0; h < 8; ++h) {
                xa[h]     = cur[h * cs + 2 * t];
                xa[8 + h] = cur[h * cs + 2 * t + 1];
            }
#pragma unroll
            for (int jj = 0; jj < 8; ++jj) {
                float ad = 0.f, as_ = 0.f;
#pragma unroll
                for (int rr = 0; rr < 16; ++rr) {
                    ad  = fmaf(xa[rr], fd[rr * 8 + jj], ad);
                    as_ = fmaf(xa[rr], fs[rr * 8 + jj], as_);
                }
                pD[jj * 520 + t]  = ad;
                sOut[jj * ss + t] = as_;
            }
        }
        __syncthreads();

        const size_t chb = (size_t)32768 * (size_t)(1024 - 2 * L);
        if (L >= 4) {
            const int nv = 4 * L;
            for (int u = tid; u < nv; u += 256) {
                int u4 = u * 4;
                int p = u4 / (8 * L);
                int rem = u4 - p * 8 * L;
                int h = rem / L;
                int t4 = rem - h * L;
                float4 v = p ? *(float4*)(sOut + h * ss + t4)
                             : *(float4*)(pD + h * 520 + t4);
                size_t row = (size_t)((tensor * 2 + p) * 8192) + (size_t)(b*8 + h) * 64 + e;
                *(float4*)(CH + chb + row * (size_t)L + t4) = v;
            }
        } else {
            for (int u = tid; u < 16 * L; u += 256) {
                int p = u / (8 * L);
                int rem = u - p * 8 * L;
                int h = rem / L;
                int t = rem - h * L;
                float v = p ? sOut[h * ss + t] : pD[h * 520 + t];
                size_t row = (size_t)((tensor * 2 + p) * 8192) + (size_t)(b*8 + h) * 64 + e;
                CH[chb + row * (size_t)L + t] = v;
            }
        }
        __syncthreads();
        cur = sOut; cs = ss;
    }
}

// ============================ forward DFT (compute-bound tiling) ============================
// MF[lvl][32768 x 32] = CH[lvl][32768 x L] . Wf[lvl][L x 32]
// grid = 9 x 256; block = 128 rows x 32 cols; thread = 4 rows x 4 cols.
__global__ __launch_bounds__(256)
void fwd_dft_k(const float* __restrict__ CH, const float* __restrict__ Wf,
               float* __restrict__ MF)
{
    __shared__ float As[32][132];
    __shared__ float Ws[32][36];
    const int tid = threadIdx.x;
    const int lvl = blockIdx.x >> 8;
    const int tile = blockIdx.x & 255;
    const int L = 512 >> lvl;
    const size_t chb = (size_t)32768 * (size_t)(1024 - 2 * L);
    const int wb = 32 * (1024 - 2 * L);
    const size_t mfb = (size_t)lvl * 1048576;
    const int rowb = tile * 128;
    const int rg = tid >> 3, cg = tid & 7;
    float acc[4][4] = {{0.f}};
    const int kw = (L < 32) ? L : 32;

    for (int k0 = 0; k0 < L; k0 += kw) {
        if (kw >= 4) {
            const int kq = kw >> 2;
            const int kqs = (kq == 8) ? 3 : (kq == 4) ? 2 : (kq == 2) ? 1 : 0;
            const int nf4 = 128 * kq;
            for (int u = tid; u < nf4; u += 256) {
                int row = u >> kqs, q = u & (kq - 1);
                float4 v = *(const float4*)(CH + chb + (size_t)(rowb + row) * L + k0 + q * 4);
                As[q*4+0][row] = v.x; As[q*4+1][row] = v.y;
                As[q*4+2][row] = v.z; As[q*4+3][row] = v.w;
            }
        } else { // L == 2
            if (tid < 256) {
                int row = tid >> 1, t = tid & 1;
                As[t][row] = CH[chb + (size_t)(rowb + row) * 2 + t];
            }
        }
        for (int u = tid; u < kw * 8; u += 256) {
            int kr = u >> 3, q = u & 7;
            *(float4*)&Ws[kr][q * 4] = *(const float4*)&Wf[wb + (k0 + kr) * 32 + q * 4];
        }
        __syncthreads();
#pragma unroll 4
        for (int kk = 0; kk < kw; ++kk) {
            float4 a4 = *(float4*)&As[kk][rg * 4];
            float4 w4 = *(float4*)&Ws[kk][cg * 4];
            acc[0][0] = fmaf(a4.x, w4.x, acc[0][0]); acc[0][1] = fmaf(a4.x, w4.y, acc[0][1]);
            acc[0][2] = fmaf(a4.x, w4.z, acc[0][2]); acc[0][3] = fmaf(a4.x, w4.w, acc[0][3]);
            acc[1][0] = fmaf(a4.y, w4.x, acc[1][0]); acc[1][1] = fmaf(a4.y, w4.y, acc[1][1]);
            acc[1][2] = fmaf(a4.y, w4.z, acc[1][2]); acc[1][3] = fmaf(a4.y, w4.w, acc[1][3]);
            acc[2][0] = fmaf(a4.z, w4.x, acc[2][0]); acc[2][1] = fmaf(a4.z, w4.y, acc[2][1]);
            acc[2][2] = fmaf(a4.z, w4.z, acc[2][2]); acc[2][3] = fmaf(a4.z, w4.w, acc[2][3]);
            acc[3][0] = fmaf(a4.w, w4.x, acc[3][0]); acc[3][1] = fmaf(a4.w, w4.y, acc[3][1]);
            acc[3][2] = fmaf(a4.w, w4.z, acc[3][2]); acc[3][3] = fmaf(a4.w, w4.w, acc[3][3]);
        }
        __syncthreads();
    }
#pragma unroll
    for (int i = 0; i < 4; ++i) {
        float4 o = {acc[i][0], acc[i][1], acc[i][2], acc[i][3]};
        *(float4*)(MF + mfb + (size_t)(rowb + rg * 4 + i) * 32 + cg * 4) = o;
    }
}

// ============================ combine: S = tanh(QF^T KF), U = S.KF ============================
__global__ __launch_bounds__(256)
void combine2_k(const float* __restrict__ MF, float* __restrict__ MUS, float* __restrict__ MUD)
{
    __shared__ float F[4][64][33];
    __shared__ float Sre[2][16][17], Sim[2][16][17];
    const int tid = threadIdx.x;
    const int lvl = blockIdx.x >> 7;
    const int bh = blockIdx.x & 127;
    const int L = 512 >> lvl;
    const int m = (L / 2 < 16) ? L / 2 : 16;
    const size_t mfb = (size_t)lvl * 1048576;
    for (int a = 0; a < 4; ++a) {
        const float* src = MF + mfb + ((size_t)a * 8192 + (size_t)bh * 64) * 32;
        for (int u = tid; u < 512; u += 256) {
            float4 v = *(const float4*)(src + u * 4);
            int ee = (u * 4) >> 5, c = (u * 4) & 31;
            F[a][ee][c] = v.x; F[a][ee][c+1] = v.y; F[a][ee][c+2] = v.z; F[a][ee][c+3] = v.w;
        }
    }
    __syncthreads();
    const int mm = m * m;
    for (int idx = tid; idx < 2 * mm; idx += 256) {
        int p = idx / mm, rr = idx - p * mm;
        int x = rr / m, y = rr - (rr / m) * m;
        float sr = 0.f, si = 0.f;
        for (int ee = 0; ee < 64; ++ee) {
            float qre = F[p][ee][x],     qim = F[p][ee][16 + x];
            float kre = F[2 + p][ee][y], kim = F[2 + p][ee][16 + y];
            sr = fmaf(qre, kre, sr); sr = fmaf(-qim, kim, sr);
            si = fmaf(qre, kim, si); si = fmaf(qim, kre, si);
        }
        float twoa = fminf(fmaxf(2.f * sr, -30.f), 30.f);
        float e2 = expf(twoa), inv = 1.f / e2;
        float s2b, c2b; sincosf(2.f * si, &s2b, &c2b);
        float den = 0.5f * (e2 + inv) + c2b;
        Sre[p][x][y] = 0.5f * (e2 - inv) / den;
        Sim[p][x][y] = s2b / den;
    }
    __syncthreads();
    for (int idx = tid; idx < 1024; idx += 256) {
        int ee = idx >> 4, x = idx & 15;
        float urd = 0.f, uid = 0.f, urs = 0.f, uis = 0.f;
        if (x < m) {
            for (int y = 0; y < m; ++y) {
                float k0re = F[2][ee][y], k0im = F[2][ee][16 + y];
                float k1re = F[3][ee][y], k1im = F[3][ee][16 + y];
                float s0r = Sre[0][x][y], s0i = Sim[0][x][y];
                float s1r = Sre[1][x][y], s1i = Sim[1][x][y];
                urd = fmaf(s0r, k0re, urd); urd = fmaf(-s0i, k0im, urd);
                uid = fmaf(s0r, k0im, uid); uid = fmaf(s0i, k0re, uid);
                urs = fmaf(s1r, k1re, urs); urs = fmaf(-s1i, k1im, urs);
                uis = fmaf(s1r, k1im, uis); uis = fmaf(s1i, k1re, uis);
            }
        }
        size_t mb = (size_t)lvl * 262144 + ((size_t)bh * 64 + ee) * 32;
        MUS[mb + x]      = urd;
        MUS[mb + 16 + x] = uid;
        MUD[mb + x]      = urd + urs;
        MUD[mb + 16 + x] = uid + uis;
    }
}

// ============================ inverse DFT (compute-bound tiling) ============================
// US/UD[lvl][8192 x L] = MU[lvl][8192 x 32] . Wi[lvl][32 x L]
// block = 128 rows x 32 t-cols; thread = 4 rows x 4 cols.
__global__ __launch_bounds__(256)
void inv_dft_k(const float* __restrict__ MUS, const float* __restrict__ MUD,
               const float* __restrict__ Wi,
               float* __restrict__ US, float* __restrict__ UD)
{
    __shared__ float As[32][132];
    __shared__ float Ws[32][36];
    const int bx = blockIdx.x;
    int lvl = 0, base = 0;
#pragma unroll
    for (int l = 0; l < 9; ++l) {
        int cl = 128 << ((l <= 4) ? (4 - l) : 0);
        if (bx < base + cl) { lvl = l; break; }
        base += cl;
    }
    const int r = bx - base;
    const int L = 512 >> lvl;
    const int tcb = (lvl <= 4) ? (4 - lvl) : 0;
    const int tile = r >> tcb;
    const int tc = r & ((1 << tcb) - 1);
    const int t0 = tc * 32;
    const int ar = tile >> 6;
    const int rowb = (tile & 63) * 128;
    const float* MU = ar ? MUD : MUS;
    float* OUT = ar ? UD : US;
    const int wb = 32 * (1024 - 2 * L);
    const size_t uoff = (size_t)8192 * (size_t)(1024 - 2 * L);
    const int nc = (L < 32) ? L : 32;
    const int tid = threadIdx.x;
    const int rg = tid >> 3, cg = tid & 7;

#pragma unroll
    for (int i = 0; i < 4; ++i) {
        int u = tid + i * 256;
        int row = u >> 3, q = u & 7;
        float4 v = *(const float4*)(MU + (size_t)lvl * 262144 + (size_t)(rowb + row) * 32 + q * 4);
        As[q*4+0][row] = v.x; As[q*4+1][row] = v.y;
        As[q*4+2][row] = v.z; As[q*4+3][row] = v.w;
    }
    if (L >= 4) {
        int ncq = nc >> 2;
        int bits = (nc == 32) ? 3 : (nc == 16) ? 2 : (nc == 8) ? 1 : 0;
        for (int u = tid; u < 32 * ncq; u += 256) {
            int kr = u >> bits, q = u & (ncq - 1);
            *(float4*)&Ws[kr][q * 4] = *(const float4*)&Wi[wb + kr * L + t0 + q * 4];
        }
    } else {
        for (int u = tid; u < 64; u += 256)
            Ws[u >> 1][u & 1] = Wi[wb + (u >> 1) * 2 + (u & 1)];
    }
    __syncthreads();
    if (cg * 4 < nc) {
        float acc[4][4] = {{0.f}};
#pragma unroll 8
        for (int kk = 0; kk < 32; ++kk) {
            float4 a4 = *(float4*)&As[kk][rg * 4];
            float4 w4 = *(float4*)&Ws[kk][cg * 4];
            acc[0][0] = fmaf(a4.x, w4.x, acc[0][0]); acc[0][1] = fmaf(a4.x, w4.y, acc[0][1]);
            acc[0][2] = fmaf(a4.x, w4.z, acc[0][2]); acc[0][3] = fmaf(a4.x, w4.w, acc[0][3]);
            acc[1][0] = fmaf(a4.y, w4.x, acc[1][0]); acc[1][1] = fmaf(a4.y, w4.y, acc[1][1]);
            acc[1][2] = fmaf(a4.y, w4.z, acc[1][2]); acc[1][3] = fmaf(a4.y, w4.w, acc[1][3]);
            acc[2][0] = fmaf(a4.z, w4.x, acc[2][0]); acc[2][1] = fmaf(a4.z, w4.y, acc[2][1]);
            acc[2][2] = fmaf(a4.z, w4.z, acc[2][2]); acc[2][3] = fmaf(a4.z, w4.w, acc[2][3]);
            acc[3][0] = fmaf(a4.w, w4.x, acc[3][0]); acc[3][1] = fmaf(a4.w, w4.y, acc[3][1]);
            acc[3][2] = fmaf(a4.w, w4.z, acc[3][2]); acc[3][3] = fmaf(a4.w, w4.w, acc[3][3]);
        }
        if (L >= 4) {
#pragma unroll
            for (int i = 0; i < 4; ++i) {
                float4 o = {acc[i][0], acc[i][1], acc[i][2], acc[i][3]};
                *(float4*)(OUT + uoff + (size_t)(rowb + rg * 4 + i) * L + t0 + cg * 4) = o;
            }
        } else {
#pragma unroll
            for (int i = 0; i < 4; ++i) {
                OUT[uoff + (size_t)(rowb + rg * 4 + i) * 2 + 0] = acc[i][0];
                OUT[uoff + (size_t)(rowb + rg * 4 + i) * 2 + 1] = acc[i][1];
            }
        }
    }
}

// ============================ fully-fused reconstruction chain ============================
__global__ __launch_bounds__(256)
void recon_all_k(const float* __restrict__ USg, const float* __restrict__ UDg,
                 const float* __restrict__ rce, const float* __restrict__ rco,
                 float* __restrict__ vT)
{
    __shared__ float v[8][1032];
    __shared__ float se[16][8];
    __shared__ float so[16][8];
    const int tid = threadIdx.x;
    const int b = blockIdx.x >> 6;
    const int e = blockIdx.x & 63;
    if (tid < 128) se[tid >> 3][tid & 7] = rce[tid];
    else { int u = tid - 128; so[u >> 3][u & 7] = rco[u]; }
    if (tid < 16) v[tid >> 1][tid & 1] = 0.f;
    __syncthreads();

    for (int i = 8; i >= 0; --i) {
        const int L = 512 >> i;
        const size_t uoff = (size_t)8192 * (1024 - 2 * L);
        const int nC = (L + 255) >> 8;
        for (int c = nC - 1; c >= 0; --c) {
            const int t = (c << 8) + tid;
            float a[16];
            const bool act = t < L;
            if (act) {
#pragma unroll
                for (int h = 0; h < 8; ++h) {
                    size_t pgl = uoff + ((size_t)((b*8 + h) * 64 + e)) * (size_t)L + t;
                    a[h]     = v[h][t] + USg[pgl];
                    a[8 + h] = UDg[pgl];
                }
            }
            __syncthreads();
            if (act) {
#pragma unroll
                for (int jj = 0; jj < 8; ++jj) {
                    float ev = 0.f, od = 0.f;
#pragma unroll
                    for (int rr = 0; rr < 16; ++rr) {
                        ev = fmaf(a[rr], se[rr][jj], ev);
                        od = fmaf(a[rr], so[rr][jj], od);
                    }
                    v[jj][2 * t]     = ev;
                    v[jj][2 * t + 1] = od;
                }
            }
            __syncthreads();
        }
    }
    for (int u = tid; u < 2048; u += 256) {
        int h = u >> 8, q4 = u & 255;
        float4 val = *(float4*)&v[h][q4 * 4];
        *(float4*)(vT + ((size_t)((b*8 + h) * 64 + e)) * 1024 + q4 * 4) = val;
    }
}

// ============================ transpose T[b][h][e][t] -> N[b][t][e*8+h] ============================
__global__ __launch_bounds__(256)
void trans_tn_k(const float* __restrict__ vT, float* __restrict__ vN)
{
    __shared__ float Ls[512][17];
    const int b = blockIdx.x >> 6;
    const int t0 = (blockIdx.x & 63) << 4;
    const int tid = threadIdx.x;
#pragma unroll
    for (int it = 0; it < 8; ++it) {
        int u = it * 256 + tid;
        int row = u >> 2, part = u & 3;
        float4 v = *(const float4*)(vT + ((size_t)b * 512 + row) * 1024 + t0 + part * 4);
        Ls[row][part*4+0] = v.x;
        Ls[row][part*4+1] = v.y;
        Ls[row][part*4+2] = v.z;
        Ls[row][part*4+3] = v.w;
    }
    __syncthreads();
#pragma unroll
    for (int it = 0; it < 8; ++it) {
        int u = it * 256 + tid;
        int cq = u & 127, tt = u >> 7;
        int c = cq * 4;
        float4 v;
        v.x = Ls[(((c+0) & 7) << 6) + ((c+0) >> 3)][tt];
        v.y = Ls[(((c+1) & 7) << 6) + ((c+1) >> 3)][tt];
        v.z = Ls[(((c+2) & 7) << 6) + ((c+2) >> 3)][tt];
        v.w = Ls[(((c+3) & 7) << 6) + ((c+3) >> 3)][tt];
        *(float4*)(vN + ((size_t)b * 1024 + t0 + tt) * 512 + c) = v;
    }
}

// ============================ driver ============================
extern "C" void kernel_launch(void* const* d_in, const int* in_sizes, int n_in,
                              void* d_out, int out_size, void* d_ws, size_t ws_size,
                              hipStream_t stream)
{
    const float* q    = (const float*)d_in[0];
    const float* k    = (const float*)d_in[1];
    const float* Lq_w = (const float*)d_in[3];
    const float* Lq_b = (const float*)d_in[4];
    const float* Lk_w = (const float*)d_in[5];
    const float* Lk_b = (const float*)d_in[6];
    const float* outw = (const float*)d_in[9];
    const float* outb = (const float*)d_in[10];
    const float* ec_s = (const float*)d_in[11];
    const float* ec_d = (const float*)d_in[12];
    const float* rc_e = (const float*)d_in[13];
    const float* rc_o = (const float*)d_in[14];

    float* ws = (float*)d_ws;
    float* qA  = ws + QA_OFF;
    float* kA  = ws + KA_OFF;
    float* CH  = ws + CH_OFF;
    float* MF  = ws + MF_OFF;
    float* MUS = ws + MUS_OFF;
    float* MUD = ws + MUD_OFF;
    float* Wf  = ws + WF_OFF;
    float* Wi  = ws + WI_OFF;
    float* vT  = CH;
    float* vN  = CH + 8388608;
    bf16_t* WT = (bf16_t*)MF;   // weight tables live in the (currently dead) MF region

    twiddle_k<<<256, 256, 0, stream>>>(Wf, Wi);
    wprep_k<<<768, 256, 0, stream>>>(Lq_w, Lk_w, outw, WT);

    dim3 gg(128, 4);
    mfma_gemm_k<true><<<gg, 256, 0, stream>>>(q, WT, WT + 262144, Lq_b, qA);
    mfma_gemm_k<true><<<gg, 256, 0, stream>>>(k, WT + 524288, WT + 786432, Lk_b, kA);

    wavelet_chain_k<<<2048, 256, 0, stream>>>(qA, kA, CH, ec_d, ec_s);
    fwd_dft_k<<<2304, 256, 0, stream>>>(CH, Wf, MF);          // overwrites WT (ok)
    combine2_k<<<1152, 256, 0, stream>>>(MF, MUS, MUD);

    wprep_k<<<768, 256, 0, stream>>>(Lq_w, Lk_w, outw, WT);   // rebuild WT (MF now dead)
    inv_dft_k<<<4480, 256, 0, stream>>>(MUS, MUD, Wi, qA, kA);
    recon_all_k<<<1024, 256, 0, stream>>>(qA, kA, rc_e, rc_o, vT);
    trans_tn_k<<<1024, 256, 0, stream>>>(vT, vN);
    mfma_gemm_k<false><<<gg, 256, 0, stream>>>(vN, WT + 1048576, WT + 1310720, outb, (float*)d_out);
}